// Round 1
// baseline (314.189 us; speedup 1.0000x reference)
//
#include <hip/hip_runtime.h>

#define D 64
#define KCODES 1024
#define PTS_PER_BLK 256
#define MTILES 16       // 16 points per M-tile
#define NT 16           // N-tiles (of 16 codes) per wave -> 256 codes/wave, 1024/block
#define WL_CAP 8192

typedef short bf16x8 __attribute__((ext_vector_type(8)));
typedef float f32x4 __attribute__((ext_vector_type(4)));

static __device__ __forceinline__ short f2bf(float f) {  // RNE fp32->bf16
  unsigned u = __float_as_uint(f);
  u += 0x7FFF + ((u >> 16) & 1);
  return (short)(u >> 16);
}

// Exact fp32 distance, bit-identical to the R1-R4 formula (4-chain fma, then
// fma(-2,dot,fn2)+en2). Packed-key atomicMin: ties -> smaller idx = first occurrence.
// fn2 now comes from LDS (s_fn2[pl]) — same bits, computed with the same fma order.
static __device__ __forceinline__ void evalExact(const float* __restrict__ inputs,
                                                 const float* __restrict__ embedT,
                                                 const float* __restrict__ en2,
                                                 const float* s_fn2,
                                                 int p0blk, int pl, int c,
                                                 unsigned long long* s_best) {
  int p = p0blk + pl;
  const float* f = inputs + (size_t)p * D;
  const float* e = embedT + (size_t)c * D;
  float a0 = 0.f, a1 = 0.f, a2 = 0.f, a3 = 0.f;
#pragma unroll
  for (int d = 0; d < D; d += 4) {
    a0 = fmaf(f[d + 0], e[d + 0], a0);
    a1 = fmaf(f[d + 1], e[d + 1], a1);
    a2 = fmaf(f[d + 2], e[d + 2], a2);
    a3 = fmaf(f[d + 3], e[d + 3], a3);
  }
  float dot = (a0 + a1) + (a2 + a3);
  float dist = fmaf(-2.f, dot, s_fn2[pl]) + en2[c];
  unsigned long long key = ((unsigned long long)__float_as_uint(dist) << 32) | (unsigned)c;
  atomicMin(&s_best[pl], key);
}

// K0: embed [64][1024] -> embedT fp32 [1024][64], embedTb bf16 [1024][64],
// en2[k] (sequential-fma order), en2max (atomicMax on bits).
__global__ void __launch_bounds__(256) vq_prep_codes(const float* __restrict__ embed,
                                                     float* __restrict__ embedT,
                                                     unsigned short* __restrict__ embedTb,
                                                     float* __restrict__ en2,
                                                     int* __restrict__ en2max_bits) {
  int k = blockIdx.x * 256 + threadIdx.x;
  float row[D];
  float s = 0.f;
#pragma unroll
  for (int d = 0; d < D; ++d) {
    float e = embed[d * KCODES + k];   // coalesced along k
    row[d] = e;
    s = fmaf(e, e, s);
  }
  en2[k] = s;
  float4* o4 = reinterpret_cast<float4*>(embedT + (size_t)k * D);
#pragma unroll
  for (int j = 0; j < 16; ++j)
    o4[j] = make_float4(row[4 * j], row[4 * j + 1], row[4 * j + 2], row[4 * j + 3]);
  unsigned us[32];
#pragma unroll
  for (int j = 0; j < 32; ++j) {
    unsigned lo = (unsigned short)f2bf(row[2 * j]);
    unsigned hi = (unsigned short)f2bf(row[2 * j + 1]);
    us[j] = lo | (hi << 16);
  }
  uint4* ob = reinterpret_cast<uint4*>(embedTb + (size_t)k * D);
#pragma unroll
  for (int j = 0; j < 8; ++j) ob[j] = make_uint4(us[4 * j], us[4 * j + 1], us[4 * j + 2], us[4 * j + 3]);
  float m = s;
#pragma unroll
  for (int off = 32; off; off >>= 1) m = fmaxf(m, __shfl_down(m, off, 64));
  if ((threadIdx.x & 63) == 0) atomicMax(en2max_bits, __float_as_int(m));
}

// K1: per block: 256 points x all 1024 codes.
// Changes vs previous round:
//  - fn2 fused in-block (identical fma order) -> prep_fn2 kernel + 33.5MB pass deleted
//  - per-WAVE screening min (margin>=2e argument holds per-wave) -> both per-M-tile
//    barriers and s_wmin deleted; main loop is barrier-free
//  - A-fragment loads software-pipelined one M-tile ahead
//  - non-temporal output stores: no write-allocate, keeps embedT/embedTb L2-resident
__global__ void __launch_bounds__(256, 2) vq_main_kernel(
    const float* __restrict__ inputs, const float* __restrict__ embedT,
    const unsigned short* __restrict__ embedTb, const float* __restrict__ en2,
    const int* __restrict__ en2max_bits,
    float* __restrict__ out_q, float* __restrict__ out_codes,
    float* __restrict__ out_idx) {
  __shared__ unsigned long long s_best[PTS_PER_BLK];
  __shared__ unsigned s_wl[WL_CAP];
  __shared__ int s_wcount;
  __shared__ float s_fn2[PTS_PER_BLK];

  const int tid = threadIdx.x;
  const int w = tid >> 6;
  const int l = tid & 63;
  const int l15 = l & 15;
  const int lg = l >> 4;                 // quad-group 0..3
  const int p0blk = blockIdx.x * PTS_PER_BLK;
  const int cbase = w * 256;

  s_best[tid] = ~0ull;
  if (tid == 0) s_wcount = 0;

  // Fused fn2: thread tid owns point p0blk+tid. Same float4 sequential-fma order
  // as the old vq_prep_fn2 -> bit-identical values. Also warms L2 for A-frags.
  {
    const float4* i4 = reinterpret_cast<const float4*>(inputs + (size_t)(p0blk + tid) * D);
    float s = 0.f;
#pragma unroll
    for (int j = 0; j < 16; ++j) {
      float4 v = i4[j];
      s = fmaf(v.x, v.x, s); s = fmaf(v.y, v.y, s);
      s = fmaf(v.z, v.z, s); s = fmaf(v.w, v.w, s);
    }
    s_fn2[tid] = s;
  }

  const float en2max = __int_as_float(*en2max_bits);

  // B fragments: B[k][n], lane holds n = cbase+16t+l15, k = kf*32 + lg*8 + j.
  bf16x8 bfr[NT][2];
#pragma unroll
  for (int t = 0; t < NT; ++t) {
    const bf16x8* bp = reinterpret_cast<const bf16x8*>(
        embedTb + (size_t)(cbase + 16 * t + l15) * D + lg * 8);
    bfr[t][0] = bp[0];   // k in [lg*8, lg*8+8)
    bfr[t][1] = bp[4];   // +32 shorts -> k in [32+lg*8, ...)
  }
  float en2v[NT];
#pragma unroll
  for (int t = 0; t < NT; ++t) en2v[t] = en2[cbase + 16 * t + l15];

  __syncthreads();  // s_best / s_wcount / s_fn2 ready

  // A pipeline: load tile 0, then prefetch mt+1 while computing mt.
  float4 A0, A1, A2, A3;
  {
    const float* arow = inputs + (size_t)(p0blk + l15) * D + lg * 8;
    A0 = *reinterpret_cast<const float4*>(arow + 0);
    A1 = *reinterpret_cast<const float4*>(arow + 4);
    A2 = *reinterpret_cast<const float4*>(arow + 32);
    A3 = *reinterpret_cast<const float4*>(arow + 36);
  }

#pragma unroll 1
  for (int mt = 0; mt < MTILES; ++mt) {
    // Prefetch next M-tile's A fragment (clamped on last iter; redundant re-load is cheap).
    const int mtn = (mt + 1 < MTILES) ? mt + 1 : mt;
    const float* an = inputs + (size_t)(p0blk + mtn * 16 + l15) * D + lg * 8;
    float4 N0 = *reinterpret_cast<const float4*>(an + 0);
    float4 N1 = *reinterpret_cast<const float4*>(an + 4);
    float4 N2 = *reinterpret_cast<const float4*>(an + 32);
    float4 N3 = *reinterpret_cast<const float4*>(an + 36);

    bf16x8 af0, af1;
    af0[0] = f2bf(A0.x); af0[1] = f2bf(A0.y); af0[2] = f2bf(A0.z); af0[3] = f2bf(A0.w);
    af0[4] = f2bf(A1.x); af0[5] = f2bf(A1.y); af0[6] = f2bf(A1.z); af0[7] = f2bf(A1.w);
    af1[0] = f2bf(A2.x); af1[1] = f2bf(A2.y); af1[2] = f2bf(A2.z); af1[3] = f2bf(A2.w);
    af1[4] = f2bf(A3.x); af1[5] = f2bf(A3.y); af1[6] = f2bf(A3.z); af1[7] = f2bf(A3.w);

    f32x4 acc[NT];
#pragma unroll
    for (int t = 0; t < NT; ++t) acc[t] = (f32x4){0.f, 0.f, 0.f, 0.f};
#pragma unroll
    for (int t = 0; t < NT; ++t)
      acc[t] = __builtin_amdgcn_mfma_f32_16x16x32_bf16(af0, bfr[t][0], acc[t], 0, 0, 0);
#pragma unroll
    for (int t = 0; t < NT; ++t)
      acc[t] = __builtin_amdgcn_mfma_f32_16x16x32_bf16(af1, bfr[t][1], acc[t], 0, 0, 0);

    // C/D layout: row(point) = lg*4 + reg, col(code) = l15 [m89/m91-verified].
    float fnv[4];
#pragma unroll
    for (int r = 0; r < 4; ++r) fnv[r] = s_fn2[mt * 16 + lg * 4 + r];
#pragma unroll
    for (int t = 0; t < NT; ++t)
#pragma unroll
      for (int r = 0; r < 4; ++r)
        acc[t][r] = fmaf(-2.f, acc[t][r], fnv[r]) + en2v[t];

    // Per-WAVE min per point (lane-local over t, butterfly over 16 cols).
    // Correctness: true argmin c* lies in some wave w*; within w*,
    // d~(c*) <= wave_min + 2e, so wave_min + margin (margin >= 2e) still
    // captures it. No cross-wave exchange, no barrier.
    float thr[4];
#pragma unroll
    for (int r = 0; r < 4; ++r) {
      float mm = acc[0][r];
#pragma unroll
      for (int t = 1; t < NT; ++t) mm = fminf(mm, acc[t][r]);
#pragma unroll
      for (int s = 1; s < 16; s <<= 1) mm = fminf(mm, __shfl_xor(mm, s, 16));
      // margin >= 2*|d~ - d| bound: bf16 u=2^-8 -> 2*2^-7*sqrt(fn2*en2) + accum slack, x2 safety.
      thr[r] = mm + (0.03125f * sqrtf(fnv[r] * en2max) + 0.01f);
    }
#pragma unroll
    for (int t = 0; t < NT; ++t)
#pragma unroll
      for (int r = 0; r < 4; ++r)
        if (acc[t][r] <= thr[r]) {
          int pl = mt * 16 + lg * 4 + r;
          int c = cbase + 16 * t + l15;
          int pos = atomicAdd(&s_wcount, 1);
          if (pos < WL_CAP) s_wl[pos] = (unsigned)((pl << 10) | c);
          else evalExact(inputs, embedT, en2, s_fn2, p0blk, pl, c, s_best);  // overflow fallback
        }

    A0 = N0; A1 = N1; A2 = N2; A3 = N3;
  }

  __syncthreads();  // worklist complete

  // Exact re-eval of the worklist (parallel across the block).
  int wc = s_wcount; if (wc > WL_CAP) wc = WL_CAP;
  for (int i = tid; i < wc; i += 256)
    evalExact(inputs, embedT, en2, s_fn2, p0blk, (int)(s_wl[i] >> 10), (int)(s_wl[i] & 1023), s_best);
  __syncthreads();

  // Outputs: 4 lanes cooperate per point; lanes 0-3 cover 64B-contiguous chunks.
  // Non-temporal: outputs are write-once / never re-read -> don't allocate L2.
  const int sub = tid & 3;
#pragma unroll 1
  for (int pass = 0; pass < 4; ++pass) {
    int pl = pass * 64 + (tid >> 2);
    unsigned long long key = s_best[pl];
    int c = (int)(unsigned)(key & 0xFFFFFFFFu);
    int p = p0blk + pl;
    const f32x4* qrow = reinterpret_cast<const f32x4*>(embedT + (size_t)c * D);
    const f32x4* frow = reinterpret_cast<const f32x4*>(inputs + (size_t)p * D);
    f32x4* oq = reinterpret_cast<f32x4*>(out_q + (size_t)p * D);
    f32x4* oc = reinterpret_cast<f32x4*>(out_codes + (size_t)p * 2 * D);
#pragma unroll
    for (int j = 0; j < 4; ++j) {
      int i4 = j * 4 + sub;
      f32x4 qv = qrow[i4];
      f32x4 fv = frow[i4];
      __builtin_nontemporal_store(qv, &oq[i4]);
      __builtin_nontemporal_store(fv, &oc[i4]);
      __builtin_nontemporal_store(qv, &oc[16 + i4]);
    }
    if (sub == 0) __builtin_nontemporal_store((float)c, &out_idx[p]);
  }
}

extern "C" void kernel_launch(void* const* d_in, const int* in_sizes, int n_in,
                              void* d_out, int out_size, void* d_ws, size_t ws_size,
                              hipStream_t stream) {
  const float* inputs = (const float*)d_in[0];
  const float* embed  = (const float*)d_in[1];
  int N = in_sizes[0] / D;  // 131072

  float* embedT          = (float*)d_ws;                             // 256 KB
  unsigned short* embedTb = (unsigned short*)(embedT + KCODES * D);  // 128 KB
  float* en2             = (float*)(embedTb + KCODES * D);           // 4 KB
  float* fn2_unused      = en2 + KCODES;                             // 512 KB (reserved, unused)
  int* en2max_bits       = (int*)(fn2_unused + N);                   // 4 B

  float* out = (float*)d_out;
  float* out_q     = out;                      // [N, 64]
  float* out_codes = out + (size_t)N * D;      // [N, 128]
  float* out_idx   = out + (size_t)N * D * 3;  // [N]

  vq_prep_codes<<<KCODES / 256, 256, 0, stream>>>(embed, embedT, embedTb, en2, en2max_bits);
  vq_main_kernel<<<N / PTS_PER_BLK, 256, 0, stream>>>(inputs, embedT, embedTb, en2,
                                                      en2max_bits, out_q, out_codes, out_idx);
}